// Round 6
// baseline (3356.450 us; speedup 1.0000x reference)
//
#include <hip/hip_runtime.h>
#include <hip/hip_bf16.h>
#include <math.h>

// ---------------------------------------------------------------------------
// Bayesian LSTM, MI355X persistent-kernel design, round 8.
//   R8 (from R7 post-mortem: W' LDS reads are the conflicts AND a first-order
//   cost, but W'-in-registers spills; sync flavor is second-order):
//   - wave->tile remap: wave w owns ONE 16-col N-tile (nt=w), BOTH M halves.
//     Each B-fragment ds_read_b128 feeds 2 MFMAs -> B-reads/CU/step halved
//     (288->144). A staged in 4 chunks x 16 uint4, double-buffered named
//     arrays (static indices), first-chunk latency only.
//   - per-wave uint flags (4/block): each wave publishes after its own
//     vmcnt(0); no pre-flag syncthreads; own-block flags subsume post-poll
//     barrier. ONE __syncthreads per step (gbuf transpose).
//   - publish overlap: h-store + ys + x-loads issued, ONE vmcnt(0) drains
//     them concurrently, then flag -> x-MFMAs -> poll.
//   - keep: LDS W' + XOR swizzle, packed h slot [64 blk][32 b][16 col],
//     epoch ring P<=16 + amortized acquire fence.
// ---------------------------------------------------------------------------

#define T_STEPS 384
#define HID 1024
#define KTOT 1152            // HID + IN
#define KPB 2304             // LDS row stride BYTES (=== 0 mod 128, 144 uint4)

// ws layout (bytes)
#define WS_WG    0ull                  // 4096*1152*2 = 9437184
#define WS_XBF   9437184ull            // 384*128*128*2 = 12582912
#define WS_BSUM  22020096ull           // 4096*4
#define WS_ACC   22036480ull           // 8 doubles
#define WS_FLAGS 22036544ull           // 4 groups * 256 * 4B = 4096
#define WS_HBUF  22040640ull           // 4 groups * P slots * 64KB
#define WS_ZERO_LEN 4160ull            // accd + flags

#define OUT_HN 50331648ull
#define OUT_CN 50462720ull
#define OUT_KL 50593792ull

typedef __bf16 bf16_t;
typedef bf16_t bf16x8 __attribute__((ext_vector_type(8)));
typedef float f32x4 __attribute__((ext_vector_type(4)));

__device__ __forceinline__ unsigned short f2bf(float f) {
  unsigned int u = __float_as_uint(f);
  u += 0x7fffu + ((u >> 16) & 1u);          // round-to-nearest-even
  return (unsigned short)(u >> 16);
}
__device__ __forceinline__ bf16x8 ld_bf16x8(const void* p) {
  union { uint4 u; bf16x8 v; } c;
  c.u = *(const uint4*)p;
  return c.v;
}
__device__ __forceinline__ bf16x8 u4bf(uint4 u) {
  union { uint4 u; bf16x8 v; } c;
  c.u = u;
  return c.v;
}
__device__ __forceinline__ float sigm(float x) { return 1.f / (1.f + __expf(-x)); }
__device__ __forceinline__ float tanh_fast(float x) {
  float ax = fabsf(x);
  float e = __expf(-2.f * ax);
  float t = (1.f - e) / (1.f + e);
  return copysignf(t, x);
}

// stage 8 k-fragments for BOTH M halves (16 uint4)
__device__ __forceinline__ void stage8(uint4* A0, uint4* A1,
                                       const unsigned short* hr0,
                                       const unsigned short* hr1, int c) {
  #pragma unroll
  for (int i = 0; i < 8; ++i) {
    A0[i] = *(const uint4*)(hr0 + (8 * c + i) * 1024);
    A1[i] = *(const uint4*)(hr1 + (8 * c + i) * 1024);
  }
}

// 8 k-fragments x {1 B-read -> 2 MFMAs}; 4 independent acc chains
__device__ __forceinline__ void mfma8(const uint4* A0, const uint4* A1,
                                      const char* WBb, int swb, int xo, int c,
                                      f32x4& a00, f32x4& a01,
                                      f32x4& a10, f32x4& a11) {
  #pragma unroll
  for (int i = 0; i < 8; ++i) {
    int kk = 8 * c + i;
    bf16x8 Bf = ld_bf16x8(WBb + ((xo + 64 * kk) ^ swb));
    bf16x8 a0 = u4bf(A0[i]);
    bf16x8 a1 = u4bf(A1[i]);
    if (i & 1) {
      a01 = __builtin_amdgcn_mfma_f32_16x16x32_bf16(a0, Bf, a01, 0, 0, 0);
      a11 = __builtin_amdgcn_mfma_f32_16x16x32_bf16(a1, Bf, a11, 0, 0, 0);
    } else {
      a00 = __builtin_amdgcn_mfma_f32_16x16x32_bf16(a0, Bf, a00, 0, 0, 0);
      a10 = __builtin_amdgcn_mfma_f32_16x16x32_bf16(a1, Bf, a10, 0, 0, 0);
    }
  }
}

// ---------------------------------------------------------------------------
__global__ __launch_bounds__(256) void prep_kernel(
    const float* __restrict__ x,
    const float* __restrict__ wim, const float* __restrict__ wir, const float* __restrict__ wie,
    const float* __restrict__ whm, const float* __restrict__ whr, const float* __restrict__ whe,
    const float* __restrict__ bim, const float* __restrict__ bir, const float* __restrict__ bie,
    const float* __restrict__ bhm, const float* __restrict__ bhr, const float* __restrict__ bhe,
    unsigned short* __restrict__ Wg, unsigned short* __restrict__ xbf,
    float* __restrict__ bsum, double* __restrict__ accd)
{
  const int NHH = 4194304, NIH = 524288, NB = 4096, NX = 6291456;
  const int NTOT = NHH + NIH + NB + NX;
  double a0=0,a1=0,a2=0,a3=0,a4=0,a5=0,a6=0,a7=0;
  int stride = gridDim.x * blockDim.x;
  for (int i = blockIdx.x * blockDim.x + threadIdx.x; i < NTOT; i += stride) {
    if (i < NHH) {                                   // w_hh -> W'[g][0:1024]
      int g = i >> 10, k = i & 1023;
      float sg = log1pf(expf(whr[i])) + 1e-5f;
      float eps = whe[i];
      float w = fmaf(sg, eps, whm[i]);
      Wg[(size_t)g * KTOT + k] = f2bf(w);
      a2 += (double)(logf(sg) + 0.5f * eps * eps);
      a3 += (double)w * (double)w;
    } else if (i < NHH + NIH) {                      // w_ih -> W'[g][1024:1152]
      int j = i - NHH;
      int g = j >> 7, k = j & 127;
      float sg = log1pf(expf(wir[j])) + 1e-5f;
      float eps = wie[j];
      float w = fmaf(sg, eps, wim[j]);
      Wg[(size_t)g * KTOT + HID + k] = f2bf(w);
      a0 += (double)(logf(sg) + 0.5f * eps * eps);
      a1 += (double)w * (double)w;
    } else if (i < NHH + NIH + NB) {                 // biases
      int k = i - NHH - NIH;
      float sg1 = log1pf(expf(bir[k])) + 1e-5f;
      float e1 = bie[k];
      float w1 = fmaf(sg1, e1, bim[k]);
      a4 += (double)(logf(sg1) + 0.5f * e1 * e1);
      a5 += (double)w1 * (double)w1;
      float sg2 = log1pf(expf(bhr[k])) + 1e-5f;
      float e2 = bhe[k];
      float w2 = fmaf(sg2, e2, bhm[k]);
      a6 += (double)(logf(sg2) + 0.5f * e2 * e2);
      a7 += (double)w2 * (double)w2;
      bsum[k] = w1 + w2;
    } else {                                         // x -> bf16
      int k = i - NHH - NIH - NB;
      xbf[k] = f2bf(x[k]);
    }
  }
  double v[8] = {a0,a1,a2,a3,a4,a5,a6,a7};
  int lane = threadIdx.x & 63, wave = threadIdx.x >> 6;
  __shared__ double red[4][8];
  #pragma unroll
  for (int q = 0; q < 8; ++q) {
    double t = v[q];
    #pragma unroll
    for (int o = 32; o > 0; o >>= 1) t += __shfl_down(t, o, 64);
    if (lane == 0) red[wave][q] = t;
  }
  __syncthreads();
  if (threadIdx.x == 0) {
    #pragma unroll
    for (int q = 0; q < 8; ++q) {
      double s = red[0][q] + red[1][q] + red[2][q] + red[3][q];
      atomicAdd(&accd[q], s);
    }
  }
}

// ---------------------------------------------------------------------------
__global__ __launch_bounds__(256, 1) void lstm_kernel(
    const unsigned short* __restrict__ Wg, const unsigned short* __restrict__ xbf,
    const float* __restrict__ bsum, unsigned short* __restrict__ hbuf,
    unsigned int* __restrict__ flags, const double* __restrict__ accd,
    float* __restrict__ out, int P)
{
  extern __shared__ char smem[];
  unsigned short* Wl = (unsigned short*)smem;                 // 64 x 2304 B
  float* gbuf = (float*)(smem + (size_t)64 * KPB);            // 32 x 68 f32
  const int tid = threadIdx.x, gid = blockIdx.x;
  const int group = gid >> 6, idx = gid & 63, j0 = idx * 16;

  if (gid == 0 && tid == 0) {
    // KL finalize (logsumexp over tensor-level sums)
    const double L2PI = 1.8378770664093453;
    const double LN_PI = -0.28768207245178085;    // ln 0.75
    const double LN_1MPI = -1.3862943611198906;   // ln 0.25
    const double INV2S1 = 3.694528049465325;      // e^2/2
    const double INV2S2 = 601302.1420823884;      // e^14/2
    double Ns[4] = {524288.0, 4194304.0, 4096.0, 4096.0};
    double kl = 0.0;
    #pragma unroll
    for (int tq = 0; tq < 4; ++tq) {
      double post_acc = accd[2*tq], w2 = accd[2*tq+1];
      double N = Ns[tq];
      double post = -0.5 * N * L2PI - post_acc;
      double m1 = -0.5 * N * L2PI + N * 1.0 - w2 * INV2S1 + LN_PI;
      double m2 = -0.5 * N * L2PI + N * 7.0 - w2 * INV2S2 + LN_1MPI;
      double mx = fmax(m1, m2), mn = fmin(m1, m2);
      double lse = mx + log1p(exp(mn - mx));
      kl += post - lse;
    }
    out[OUT_KL] = (float)kl;
  }

  // Load this block's 64 W'-rows into LDS, XOR-swizzled (slot ^= row&7).
  {
    int r = tid >> 2, c4 = tid & 3;
    int grow = ((r >> 4) << 10) + j0 + (r & 15);
    const uint4* src = (const uint4*)(Wg + (size_t)grow * KTOT);
    uint4* dst = (uint4*)(smem + (size_t)r * KPB);
    int sw = r & 7;
    #pragma unroll
    for (int j = 0; j < 36; ++j) dst[(c4 + 4 * j) ^ sw] = src[c4 + 4 * j];
  }

  const int lane = tid & 63, wave = tid >> 6;
  const int lq = lane >> 4, ln = lane & 15;

  // wave w owns N-tile nt=w (rows w*16+ln of LDS W'), BOTH M halves.
  const char* WBb = (const char*)Wl + (size_t)(wave * 16 + ln) * KPB;
  const int swb = (ln & 7) << 4;                  // XOR on byte bits 4-6
  const int xo = 16 * lq;

  unsigned short* hgrp = hbuf + (size_t)group * (size_t)P * 32768;
  const unsigned short* xrow0 = xbf + (size_t)(group * 32 + ln) * 128 + 8 * lq;
  const unsigned short* xrow1 = xrow0 + 16 * 128;
  unsigned int* flg = flags + group * 256;
  // A-frag bases into packed slot [64 blk][32 b][16 col] (shorts)
  const int hb0 = (lq >> 1) * 512 + ln * 16 + 8 * (lq & 1);
  const int hb1 = hb0 + 256;                      // rows 16..31

  // nonlinearity mapping: thread -> (batch b, 2 consecutive j's)
  const int b = tid >> 3, jj0 = (tid & 7) * 2;
  const float2 bi0 = *(const float2*)&bsum[j0 + jj0];
  const float2 bi1 = *(const float2*)&bsum[1024 + j0 + jj0];
  const float2 bi2 = *(const float2*)&bsum[2048 + j0 + jj0];
  const float2 bi3 = *(const float2*)&bsum[3072 + j0 + jj0];
  float c0 = 0.f, c1 = 0.f;

  __syncthreads();

  // prologue: x-part of step 0 into accx (h_{-1}=0 -> h-GEMM skipped at t=0)
  f32x4 accx0 = {0.f,0.f,0.f,0.f}, accx1 = {0.f,0.f,0.f,0.f};
  #pragma unroll
  for (int kk = 0; kk < 4; ++kk) {
    bf16x8 bx = ld_bf16x8(WBb + 2048 + ((xo + 64 * kk) ^ swb));
    bf16x8 a0 = ld_bf16x8(xrow0 + 32 * kk);
    bf16x8 a1 = ld_bf16x8(xrow1 + 32 * kk);
    accx0 = __builtin_amdgcn_mfma_f32_16x16x32_bf16(a0, bx, accx0, 0, 0, 0);
    accx1 = __builtin_amdgcn_mfma_f32_16x16x32_bf16(a1, bx, accx1, 0, 0, 0);
  }

  for (int t = 0; t < T_STEPS; ++t) {
    f32x4 acc0, acc1;
    if (t > 0) {
      // epoch boundary: one amortized acquire (cache inv) per P steps
      if (((t - 1) & (P - 1)) == 0) {
        __builtin_amdgcn_fence(__ATOMIC_ACQUIRE, "agent");
        __builtin_amdgcn_sched_barrier(0);
      }
      const unsigned short* hs = hgrp + (size_t)((t - 1) & (P - 1)) * 32768;
      const unsigned short* hr0 = hs + hb0;
      const unsigned short* hr1 = hs + hb1;
      uint4 Aa0[8], Aa1[8], Ab0[8], Ab1[8];
      f32x4 a00 = accx0, a01 = {0.f,0.f,0.f,0.f};
      f32x4 a10 = accx1, a11 = {0.f,0.f,0.f,0.f};
      stage8(Aa0, Aa1, hr0, hr1, 0);  __builtin_amdgcn_sched_barrier(0);
      stage8(Ab0, Ab1, hr0, hr1, 1);  __builtin_amdgcn_sched_barrier(0);
      mfma8(Aa0, Aa1, WBb, swb, xo, 0, a00, a01, a10, a11);
      stage8(Aa0, Aa1, hr0, hr1, 2);  __builtin_amdgcn_sched_barrier(0);
      mfma8(Ab0, Ab1, WBb, swb, xo, 1, a00, a01, a10, a11);
      stage8(Ab0, Ab1, hr0, hr1, 3);  __builtin_amdgcn_sched_barrier(0);
      mfma8(Aa0, Aa1, WBb, swb, xo, 2, a00, a01, a10, a11);
      mfma8(Ab0, Ab1, WBb, swb, xo, 3, a00, a01, a10, a11);
      acc0 = a00 + a01;
      acc1 = a10 + a11;
    } else {
      acc0 = accx0;
      acc1 = accx1;
    }
    // C layout per mt: col=lane&15, row=(lane>>4)*4+r
    #pragma unroll
    for (int r = 0; r < 4; ++r) {
      gbuf[(lq * 4 + r) * 68 + wave * 16 + ln] = acc0[r];
      gbuf[(16 + lq * 4 + r) * 68 + wave * 16 + ln] = acc1[r];
    }
    __syncthreads();

    // gate nonlinearity: (b, jj0), (b, jj0+1); c-state in registers
    float2 gi = *(const float2*)&gbuf[b * 68 + jj0];
    float2 gf = *(const float2*)&gbuf[b * 68 + 16 + jj0];
    float2 gg = *(const float2*)&gbuf[b * 68 + 32 + jj0];
    float2 go = *(const float2*)&gbuf[b * 68 + 48 + jj0];
    float c0n = sigm(gf.x + bi1.x) * c0 + sigm(gi.x + bi0.x) * tanh_fast(gg.x + bi2.x);
    float c1n = sigm(gf.y + bi1.y) * c1 + sigm(gi.y + bi0.y) * tanh_fast(gg.y + bi2.y);
    float h0 = sigm(go.x + bi3.x) * tanh_fast(c0n);
    float h1 = sigm(go.y + bi3.y) * tanh_fast(c1n);
    c0 = c0n; c1 = c1n;
    const bool last_t = (t == T_STEPS - 1);

    if (!last_t) {
      // h feedback first (oldest vm op; drain overlapped with ys/x below)
      unsigned int* hw32 = (unsigned int*)(hgrp + (size_t)(t & (P - 1)) * 32768);
      unsigned int pk = (unsigned)f2bf(h0) | ((unsigned)f2bf(h1) << 16);
      __hip_atomic_store(&hw32[idx * 256 + tid], pk,
                         __ATOMIC_RELAXED, __HIP_MEMORY_SCOPE_AGENT);
      __builtin_amdgcn_sched_barrier(0);
    }
    // ys / hn / cn stores (issued before the drain -> overlap)
    {
      size_t bg = (size_t)(group * 32 + b);
      float2 hs = {h0, h1};
      *(float2*)&out[(size_t)t * 131072 + bg * 1024 + j0 + jj0] = hs;
      if (last_t) {
        *(float2*)&out[OUT_HN + bg * 1024 + j0 + jj0] = hs;
        float2 cs = {c0n, c1n};
        *(float2*)&out[OUT_CN + bg * 1024 + j0 + jj0] = cs;
      }
    }
    if (!last_t) {
      // x-loads for t+1 (issued pre-drain; latency overlaps h-store ack)
      uint4 xa0[4], xa1[4];
      const unsigned short* xr0 = xrow0 + (size_t)(t + 1) * 16384;
      const unsigned short* xr1 = xrow1 + (size_t)(t + 1) * 16384;
      #pragma unroll
      for (int kk = 0; kk < 4; ++kk) {
        xa0[kk] = *(const uint4*)(xr0 + 32 * kk);
        xa1[kk] = *(const uint4*)(xr1 + 32 * kk);
      }
      asm volatile("s_waitcnt vmcnt(0)" ::: "memory");
      __builtin_amdgcn_sched_barrier(0);
      // per-wave flag: this wave's h chunk is at the coherence point
      if (lane == 0)
        __hip_atomic_store(&flg[idx * 4 + wave], (unsigned)(t + 1),
                           __ATOMIC_RELAXED, __HIP_MEMORY_SCOPE_AGENT);
      // x-part MFMAs for t+1 (data already arrived with the drain)
      accx0 = (f32x4){0.f,0.f,0.f,0.f};
      accx1 = (f32x4){0.f,0.f,0.f,0.f};
      #pragma unroll
      for (int kk = 0; kk < 4; ++kk) {
        bf16x8 bx = ld_bf16x8(WBb + 2048 + ((xo + 64 * kk) ^ swb));
        accx0 = __builtin_amdgcn_mfma_f32_16x16x32_bf16(u4bf(xa0[kk]), bx, accx0, 0, 0, 0);
        accx1 = __builtin_amdgcn_mfma_f32_16x16x32_bf16(u4bf(xa1[kk]), bx, accx1, 0, 0, 0);
      }

      // flag barrier: all waves poll all 256 per-wave flags (4 uints/lane).
      // Own-block flags subsume the intra-block barrier (gbuf safe).
      const unsigned tgt = (unsigned)(t + 1);
      const unsigned int* fp = flg + 4 * lane;
      while (true) {
        unsigned f0 = __hip_atomic_load(fp + 0, __ATOMIC_RELAXED, __HIP_MEMORY_SCOPE_AGENT);
        unsigned f1 = __hip_atomic_load(fp + 1, __ATOMIC_RELAXED, __HIP_MEMORY_SCOPE_AGENT);
        unsigned f2 = __hip_atomic_load(fp + 2, __ATOMIC_RELAXED, __HIP_MEMORY_SCOPE_AGENT);
        unsigned f3 = __hip_atomic_load(fp + 3, __ATOMIC_RELAXED, __HIP_MEMORY_SCOPE_AGENT);
        unsigned mn = min(min(f0, f1), min(f2, f3));
        if (!__ballot(mn < tgt)) break;
        __builtin_amdgcn_s_sleep(1);
      }
      __builtin_amdgcn_sched_barrier(0);         // pin next h-loads below poll
    }
  }
}

// ---------------------------------------------------------------------------
extern "C" void kernel_launch(void* const* d_in, const int* in_sizes, int n_in,
                              void* d_out, int out_size, void* d_ws, size_t ws_size,
                              hipStream_t stream) {
  const float* x   = (const float*)d_in[0];
  const float* wim = (const float*)d_in[1];
  const float* wir = (const float*)d_in[2];
  const float* wie = (const float*)d_in[3];
  const float* whm = (const float*)d_in[4];
  const float* whr = (const float*)d_in[5];
  const float* whe = (const float*)d_in[6];
  const float* bim = (const float*)d_in[7];
  const float* bir = (const float*)d_in[8];
  const float* bie = (const float*)d_in[9];
  const float* bhm = (const float*)d_in[10];
  const float* bhr = (const float*)d_in[11];
  const float* bhe = (const float*)d_in[12];
  char* ws = (char*)d_ws;
  unsigned short* Wg    = (unsigned short*)(ws + WS_WG);
  unsigned short* xbf   = (unsigned short*)(ws + WS_XBF);
  float*          bsum  = (float*)(ws + WS_BSUM);
  double*         accd  = (double*)(ws + WS_ACC);
  unsigned int*   flags = (unsigned int*)(ws + WS_FLAGS);
  unsigned short* hbuf  = (unsigned short*)(ws + WS_HBUF);
  float* out = (float*)d_out;

  // epoch ring size: largest power-of-two slot count (<=16) that fits ws
  size_t avail = (ws_size > WS_HBUF) ? ws_size - WS_HBUF : (size_t)0;
  int P = 2;
  while (P < 16 && (size_t)(P * 2) * 4ull * 65536ull <= avail) P *= 2;

  hipMemsetAsync(ws + WS_ACC, 0, WS_ZERO_LEN, stream);
  prep_kernel<<<dim3(1024), dim3(256), 0, stream>>>(
      x, wim, wir, wie, whm, whr, whe, bim, bir, bie, bhm, bhr, bhe,
      Wg, xbf, bsum, accd);

  const int SMEM = 64 * KPB + 32 * 68 * 4;   // 156160 B
  hipFuncSetAttribute((const void*)lstm_kernel,
                      hipFuncAttributeMaxDynamicSharedMemorySize, SMEM);
  const unsigned short* Wg_c = Wg; const unsigned short* xbf_c = xbf;
  const float* bsum_c = bsum; const double* acc_c = accd;
  void* args[] = {(void*)&Wg_c, (void*)&xbf_c, (void*)&bsum_c,
                  (void*)&hbuf, (void*)&flags, (void*)&acc_c, (void*)&out,
                  (void*)&P};
  hipError_t e = hipLaunchCooperativeKernel((void*)lstm_kernel, dim3(256), dim3(256),
                                            args, (unsigned)SMEM, stream);
  if (e != hipSuccess) {
    // fallback: 256 blocks / 256 CUs at 1 block/CU are co-resident in practice
    lstm_kernel<<<dim3(256), dim3(256), SMEM, stream>>>(Wg_c, xbf_c, bsum_c,
                                                        hbuf, flags, acc_c, out,
                                                        P);
  }
}